// Round 1
// baseline (479.467 us; speedup 1.0000x reference)
//
#include <hip/hip_runtime.h>
#include <math.h>

// STGCN layer: N=50000 nodes, E=800000 edges, C_IN=C_OUT=64, T=4, KT=3.
// Pipeline:
//   1. zero counts
//   2. fill: bucket edges by dst (CSR with fixed capacity), count degrees
//   3. dinv[n] = 1/sqrt(deg+1)
//   4. gather: y[n,c,t] = sum_{e:dst=n} dinv[src]*dinv[n]*x[src,c,t] + dinv[n]^2*x[n,c,t]
//   5. node:   out[n,o,t] = sum_c y[n,c,t]*Wg[c,o] + conv_t(x[n], Wt[o]) + bg[o] + bt[o]
// Uses the linearity of Wg to aggregate x instead of h (saves a full h pass).

#define CAP 80   // max bucket capacity; expected max degree ~45 for 800k edges / 50k nodes

__global__ __launch_bounds__(256) void zero_kernel(unsigned* __restrict__ cnt, int N) {
    int n = blockIdx.x * 256 + threadIdx.x;
    if (n < N) cnt[n] = 0u;
}

__global__ __launch_bounds__(256) void fill_kernel(const int* __restrict__ ei,
                                                   unsigned* __restrict__ cnt,
                                                   int* __restrict__ csr, int E) {
    int e = blockIdx.x * 256 + threadIdx.x;
    if (e >= E) return;
    int s = ei[e];        // row 0: src
    int d = ei[E + e];    // row 1: dst
    unsigned slot = atomicAdd(&cnt[d], 1u);
    if (slot < CAP) csr[(size_t)d * CAP + slot] = s;
}

__global__ __launch_bounds__(256) void dinv_kernel(const unsigned* __restrict__ cnt,
                                                   float* __restrict__ dinv, int N) {
    int n = blockIdx.x * 256 + threadIdx.x;
    if (n >= N) return;
    dinv[n] = 1.0f / sqrtf((float)cnt[n] + 1.0f);
}

// One wave (64 lanes) per node; lane j owns float4 j of the node's 256 floats.
__global__ __launch_bounds__(256) void gather_kernel(const float* __restrict__ x,
                                                     const int* __restrict__ csr,
                                                     const unsigned* __restrict__ cnt,
                                                     const float* __restrict__ dinv,
                                                     float* __restrict__ y, int N) {
    int n = (blockIdx.x * 256 + threadIdx.x) >> 6;
    int lane = threadIdx.x & 63;
    if (n >= N) return;
    int m = (int)cnt[n];
    if (m > CAP) m = CAP;
    float di = dinv[n];
    const float4* x4 = (const float4*)x;
    const int* row = csr + (size_t)n * CAP;
    float4 acc = make_float4(0.f, 0.f, 0.f, 0.f);
    for (int i = 0; i < m; ++i) {
        int s = row[i];                      // same addr across wave -> broadcast
        float w = di * dinv[s];
        float4 xv = x4[(size_t)s * 64 + lane];  // contiguous 1KB per edge across wave
        acc.x += xv.x * w; acc.y += xv.y * w;
        acc.z += xv.z * w; acc.w += xv.w * w;
    }
    float4 xs = x4[(size_t)n * 64 + lane];
    float d2 = di * di;
    acc.x += xs.x * d2; acc.y += xs.y * d2;
    acc.z += xs.z * d2; acc.w += xs.w * d2;
    ((float4*)y)[(size_t)n * 64 + lane] = acc;
}

// Block = 256 threads = 4 waves; each wave handles 2 nodes, lane = output channel o.
// Wt staged transposed in LDS with pad-65 rows: read lds[(c*3+k)*65+o] is conflict-free
// (lanes o consecutive -> 2 lanes/bank), staging write stride 65 rotates banks.
__global__ __launch_bounds__(256) void node_kernel(const float* __restrict__ x,
                                                   const float* __restrict__ y,
                                                   const float* __restrict__ Wg,
                                                   const float* __restrict__ bg,
                                                   const float* __restrict__ Wt,
                                                   const float* __restrict__ bt,
                                                   float* __restrict__ out, int N) {
    __shared__ float wt_s[192 * 65];
    {
        const float4* Wt4 = (const float4*)Wt;
        for (int i4 = threadIdx.x; i4 < 3072; i4 += 256) {
            float4 v = Wt4[i4];
            float vv[4] = {v.x, v.y, v.z, v.w};
            int base = i4 * 4;
            #pragma unroll
            for (int j = 0; j < 4; ++j) {
                int idx = base + j;
                int o = idx / 192, ck = idx % 192;   // Wt is [o][c][k] -> store [ck][o]
                wt_s[ck * 65 + o] = vv[j];
            }
        }
    }
    __syncthreads();

    int wave = threadIdx.x >> 6;
    int o = threadIdx.x & 63;
    int n0 = blockIdx.x * 8 + wave * 2;
    if (n0 >= N) return;

    const float4* x4 = (const float4*)x;
    const float4* y4 = (const float4*)y;
    float4 A0 = make_float4(0.f,0.f,0.f,0.f), A1 = A0, T0 = A0, T1 = A0;

    for (int c = 0; c < 64; ++c) {
        float wg = Wg[c * 64 + o];                 // coalesced, L1-hot (16KB)
        float w0 = wt_s[(c * 3 + 0) * 65 + o];
        float w1 = wt_s[(c * 3 + 1) * 65 + o];
        float w2 = wt_s[(c * 3 + 2) * 65 + o];
        float4 ya = y4[(size_t)n0 * 64 + c];       // wave-broadcast 16B
        float4 xa = x4[(size_t)n0 * 64 + c];
        float4 yb = y4[(size_t)(n0 + 1) * 64 + c];
        float4 xb = x4[(size_t)(n0 + 1) * 64 + c];

        A0.x += ya.x * wg; A0.y += ya.y * wg; A0.z += ya.z * wg; A0.w += ya.w * wg;
        A1.x += yb.x * wg; A1.y += yb.y * wg; A1.z += yb.z * wg; A1.w += yb.w * wg;

        // temporal conv, pad=1: t'=t+k-1, zero outside [0,4)
        T0.x += xa.x * w1 + xa.y * w2;
        T0.y += xa.x * w0 + xa.y * w1 + xa.z * w2;
        T0.z += xa.y * w0 + xa.z * w1 + xa.w * w2;
        T0.w += xa.z * w0 + xa.w * w1;

        T1.x += xb.x * w1 + xb.y * w2;
        T1.y += xb.x * w0 + xb.y * w1 + xb.z * w2;
        T1.z += xb.y * w0 + xb.z * w1 + xb.w * w2;
        T1.w += xb.z * w0 + xb.w * w1;
    }

    float bb = bg[o] + bt[o];
    float4 r0 = make_float4(A0.x + T0.x + bb, A0.y + T0.y + bb,
                            A0.z + T0.z + bb, A0.w + T0.w + bb);
    float4 r1 = make_float4(A1.x + T1.x + bb, A1.y + T1.y + bb,
                            A1.z + T1.z + bb, A1.w + T1.w + bb);
    ((float4*)out)[(size_t)n0 * 64 + o] = r0;
    ((float4*)out)[(size_t)(n0 + 1) * 64 + o] = r1;
}

extern "C" void kernel_launch(void* const* d_in, const int* in_sizes, int n_in,
                              void* d_out, int out_size, void* d_ws, size_t ws_size,
                              hipStream_t stream) {
    const float* x  = (const float*)d_in[0];
    const int*   ei = (const int*)d_in[1];
    const float* Wg = (const float*)d_in[2];
    const float* bg = (const float*)d_in[3];
    const float* Wt = (const float*)d_in[4];
    const float* bt = (const float*)d_in[5];
    float* out = (float*)d_out;

    int N = in_sizes[0] / 256;   // C_IN*T = 256 floats per node -> 50000
    int E = in_sizes[1] / 2;     // 800000

    // workspace layout (bytes):
    //   [0, N*4)            dinv
    //   [256K, 256K+N*4)    cnt
    //   [512K, 512K+N*CAP*4) csr          (~16 MB)
    //   [y_off, y_off+N*256*4) y          (~51.2 MB)
    char* ws = (char*)d_ws;
    float*    dinv = (float*)ws;
    unsigned* cnt  = (unsigned*)(ws + (1 << 18));
    int*      csr  = (int*)(ws + (1 << 19));
    size_t csr_bytes = (size_t)N * CAP * 4;
    size_t y_off = ((1 << 19) + csr_bytes + 1023) & ~(size_t)1023;
    float* y = (float*)(ws + y_off);

    zero_kernel<<<(N + 255) / 256, 256, 0, stream>>>(cnt, N);
    fill_kernel<<<(E + 255) / 256, 256, 0, stream>>>(ei, cnt, csr, E);
    dinv_kernel<<<(N + 255) / 256, 256, 0, stream>>>(cnt, dinv, N);
    gather_kernel<<<(N + 3) / 4, 256, 0, stream>>>(x, csr, cnt, dinv, y, N);
    node_kernel<<<(N + 7) / 8, 256, 0, stream>>>(x, y, Wg, bg, Wt, bt, out, N);
}